// Round 4
// baseline (101.240 us; speedup 1.0000x reference)
//
#include <hip/hip_runtime.h>
#include <math.h>

#define OUT_H 7
#define OUT_W 7
#define N_C 256
#define N_IMG 2
#define FH 38
#define FW 38
#define HW (FH * FW)           // 1444 spatial positions
#define NUM_ROIS 256
#define SPATIAL_SCALE 0.0625f
#define IJ_CHUNK 25            // outputs per block (49 split into 25+24)

// ---------------------------------------------------------------------------
// Kernel 1: NCHW -> NHWC transpose of feat into d_ws.
// featT[b][p][c], c contiguous (256 floats = 1 KB per spatial position).
// Tiled 64x64 through LDS (+1 pad), both global sides coalesced.
// ---------------------------------------------------------------------------
__global__ __launch_bounds__(256) void transpose_nchw_nhwc(
    const float* __restrict__ feat, float* __restrict__ featT)
{
    __shared__ float tile[64][65];

    const int bid = blockIdx.x;            // N_IMG * 23 * 4 = 184
    const int b   = bid / (23 * 4);
    const int rem = bid % (23 * 4);
    const int p0  = (rem / 4) * 64;        // spatial tile
    const int c0  = (rem % 4) * 64;        // channel tile
    const int tx  = threadIdx.x & 63;
    const int tz  = threadIdx.x >> 6;      // 0..3

    const int p = p0 + tx;
    if (p < HW) {
        #pragma unroll
        for (int s = 0; s < 64; s += 4) {
            const int cl = tz + s;
            tile[cl][tx] = feat[((size_t)(b * N_C + c0 + cl)) * HW + p];
        }
    }
    __syncthreads();
    #pragma unroll
    for (int s = 0; s < 64; s += 4) {
        const int pl = tz + s;
        const int pp = p0 + pl;
        if (pp < HW)
            featT[((size_t)(b * HW + pp)) * N_C + c0 + tx] = tile[tx][pl];
    }
}

// ---------------------------------------------------------------------------
// Kernel 2: ROI max-pool, lanes = channels (ZERO divergence).
// Block = (roi, ij-half). Wave lane L owns channels 4L..4L+3 (one float4).
// Window bounds depend only on (roi, i, j) -> wave-uniform; every global
// load is dwordx4 at 16 B/lane stride = 1 KB/wave, fully coalesced, all
// independent (deep MLP). featT (3 MB) is per-XCD-L2 resident.
// Output transposed back via 25.6 KB LDS tile -> coalesced global stores.
// ---------------------------------------------------------------------------
__global__ __launch_bounds__(256) void roi_pool_nhwc(
    const float* __restrict__ featT,
    const float* __restrict__ rois,
    float* __restrict__ out)
{
    __shared__ float s_out[N_C * IJ_CHUNK];   // [c][k], row stride IJ_CHUNK

    const int bid  = blockIdx.x;
    const int r    = bid >> 1;
    const int hf   = bid & 1;
    const int s0   = hf * IJ_CHUNK;                       // 0 or 25
    const int e0   = (hf == 0) ? IJ_CHUNK : (OUT_H * OUT_W); // 25 or 49
    const int lane = threadIdx.x & 63;
    const int wv   = threadIdx.x >> 6;

    const float* roi = rois + (size_t)r * 5;
    const int b  = (int)roi[0];
    const int x1 = (int)(roi[1] * SPATIAL_SCALE);  // floor (inputs >= 0)
    const int y1 = (int)(roi[2] * SPATIAL_SCALE);
    const int x2 = (int)(roi[3] * SPATIAL_SCALE);
    const int y2 = (int)(roi[4] * SPATIAL_SCALE);
    const int rh = y2 - y1 + 1;
    const int rw = x2 - x1 + 1;

    // lane's float4 channel group, at spatial-position stride 64 float4s
    const float4* fb = (const float4*)(featT + (size_t)b * HW * N_C) + lane;

    for (int ij = s0 + wv; ij < e0; ij += 4) {
        const int i = ij / OUT_W;
        const int j = ij % OUT_W;
        const int hs = y1 + (i * rh) / OUT_H;                  // floor-div
        const int he = y1 + ((i + 1) * rh + OUT_H - 1) / OUT_H;
        const int ws = x1 + (j * rw) / OUT_W;
        const int we = x1 + ((j + 1) * rw + OUT_W - 1) / OUT_W;

        float4 m = make_float4(-INFINITY, -INFINITY, -INFINITY, -INFINITY);
        for (int h = hs; h < he; ++h) {                        // wave-uniform
            const int rowoff = h * FW;
            for (int w = ws; w < we; ++w) {
                const float4 v = fb[(size_t)(rowoff + w) * (N_C / 4)];
                m.x = fmaxf(m.x, v.x);
                m.y = fmaxf(m.y, v.y);
                m.z = fmaxf(m.z, v.z);
                m.w = fmaxf(m.w, v.w);
            }
        }
        const int k = ij - s0;
        s_out[(4 * lane + 0) * IJ_CHUNK + k] = m.x;
        s_out[(4 * lane + 1) * IJ_CHUNK + k] = m.y;
        s_out[(4 * lane + 2) * IJ_CHUNK + k] = m.z;
        s_out[(4 * lane + 3) * IJ_CHUNK + k] = m.w;
    }
    __syncthreads();

    // Coalesced copy-out: out[r][c][s0+k] <- s_out[c][k]
    float* outr = out + (size_t)r * N_C * (OUT_H * OUT_W);
    for (int idx = threadIdx.x; idx < N_C * IJ_CHUNK; idx += 256) {
        const int c = idx / IJ_CHUNK;          // const divide
        const int k = idx - c * IJ_CHUNK;
        if (s0 + k < OUT_H * OUT_W)
            outr[(size_t)c * (OUT_H * OUT_W) + s0 + k] = s_out[idx];
    }
}

extern "C" void kernel_launch(void* const* d_in, const int* in_sizes, int n_in,
                              void* d_out, int out_size, void* d_ws, size_t ws_size,
                              hipStream_t stream) {
    const float* feat = (const float*)d_in[0];
    const float* rois = (const float*)d_in[1];
    float* out   = (float*)d_out;
    float* featT = (float*)d_ws;   // 2*1444*256*4 = 2.96 MB << ws_size

    transpose_nchw_nhwc<<<N_IMG * 23 * 4, 256, 0, stream>>>(feat, featT);
    roi_pool_nhwc<<<NUM_ROIS * 2, 256, 0, stream>>>(featT, rois, out);
}

// Round 5
// 82.149 us; speedup vs baseline: 1.2324x; 1.2324x over previous
//
#include <hip/hip_runtime.h>
#include <math.h>

#define OUT_H 7
#define OUT_W 7
#define N_C 256
#define N_IMG 2
#define FH 38
#define FW 38
#define HW (FH * FW)           // 1444 spatial positions
#define NUM_ROIS 256
#define N_OUT_POS (NUM_ROIS * OUT_H * OUT_W)   // 12544 (r,ij) outputs
#define SPATIAL_SCALE 0.0625f

// featT occupies d_ws[0 .. 2*1444*256) floats; outT follows (16B aligned).
#define FEATT_FLOATS (N_IMG * HW * N_C)        // 739,328
#define OUTT_OFF FEATT_FLOATS

// ---------------------------------------------------------------------------
// K1: NCHW -> NHWC transpose of feat. featT[b][p][c], c contiguous.
// ---------------------------------------------------------------------------
__global__ __launch_bounds__(256) void transpose_nchw_nhwc(
    const float* __restrict__ feat, float* __restrict__ featT)
{
    __shared__ float tile[64][65];
    const int bid = blockIdx.x;            // N_IMG * 23 * 4 = 184
    const int b   = bid / (23 * 4);
    const int rem = bid % (23 * 4);
    const int p0  = (rem / 4) * 64;
    const int c0  = (rem % 4) * 64;
    const int tx  = threadIdx.x & 63;
    const int tz  = threadIdx.x >> 6;

    const int p = p0 + tx;
    if (p < HW) {
        #pragma unroll
        for (int s = 0; s < 64; s += 4)
            tile[tz + s][tx] = feat[((size_t)(b * N_C + c0 + tz + s)) * HW + p];
    }
    __syncthreads();
    #pragma unroll
    for (int s = 0; s < 64; s += 4) {
        const int pp = p0 + tz + s;
        if (pp < HW)
            featT[((size_t)(b * HW + pp)) * N_C + c0 + tx] = tile[tx][tz + s];
    }
}

// ---------------------------------------------------------------------------
// K2: one WAVE per (roi, ij) output position; lane owns channels 4L..4L+3.
// Window bounds wave-uniform (zero divergence); every load = 1 KB coalesced
// dwordx4 from L2-resident featT; two accumulators halve the fmax chain.
// 12544 waves -> ~12 blocks/CU: latency hidden, imbalance averaged out.
// Stores: one coalesced 1 KB wave-store to outT[r][ij][c].
// ---------------------------------------------------------------------------
__global__ __launch_bounds__(256) void roi_pool_wavepos(
    const float* __restrict__ featT,
    const float* __restrict__ rois,
    float4* __restrict__ outT)
{
    const int lane = threadIdx.x & 63;
    const int wv   = threadIdx.x >> 6;
    const int g    = blockIdx.x * 4 + wv;          // 0 .. 12543 exactly
    const int r    = g / 49;
    const int ij   = g - r * 49;
    const int i    = ij / OUT_W;
    const int j    = ij - i * OUT_W;

    const float* roi = rois + (size_t)r * 5;
    const int b  = (int)roi[0];
    const int x1 = (int)(roi[1] * SPATIAL_SCALE);  // floor (inputs >= 0)
    const int y1 = (int)(roi[2] * SPATIAL_SCALE);
    const int x2 = (int)(roi[3] * SPATIAL_SCALE);
    const int y2 = (int)(roi[4] * SPATIAL_SCALE);
    const int rh = y2 - y1 + 1;
    const int rw = x2 - x1 + 1;

    const int hs = y1 + (i * rh) / OUT_H;          // Python floor-div (>=0)
    const int he = y1 + ((i + 1) * rh + OUT_H - 1) / OUT_H;
    const int ws = x1 + (j * rw) / OUT_W;
    const int we = x1 + ((j + 1) * rw + OUT_W - 1) / OUT_W;

    const float4* fb = (const float4*)featT + (size_t)b * HW * (N_C / 4) + lane;

    float4 m0 = make_float4(-INFINITY, -INFINITY, -INFINITY, -INFINITY);
    float4 m1 = m0;
    for (int h = hs; h < he; ++h) {
        const float4* rowp = fb + (size_t)(h * FW) * (N_C / 4);
        int w = ws;
        for (; w + 1 < we; w += 2) {
            const float4 v0 = rowp[(size_t)w * (N_C / 4)];
            const float4 v1 = rowp[(size_t)(w + 1) * (N_C / 4)];
            m0.x = fmaxf(m0.x, v0.x); m0.y = fmaxf(m0.y, v0.y);
            m0.z = fmaxf(m0.z, v0.z); m0.w = fmaxf(m0.w, v0.w);
            m1.x = fmaxf(m1.x, v1.x); m1.y = fmaxf(m1.y, v1.y);
            m1.z = fmaxf(m1.z, v1.z); m1.w = fmaxf(m1.w, v1.w);
        }
        if (w < we) {
            const float4 v0 = rowp[(size_t)w * (N_C / 4)];
            m0.x = fmaxf(m0.x, v0.x); m0.y = fmaxf(m0.y, v0.y);
            m0.z = fmaxf(m0.z, v0.z); m0.w = fmaxf(m0.w, v0.w);
        }
    }
    m0.x = fmaxf(m0.x, m1.x); m0.y = fmaxf(m0.y, m1.y);
    m0.z = fmaxf(m0.z, m1.z); m0.w = fmaxf(m0.w, m1.w);

    outT[(size_t)g * 64 + lane] = m0;              // coalesced 1 KB / wave
}

// ---------------------------------------------------------------------------
// K3: outT[r][ij][c] -> out[r][c][ij]. Block = (roi, 64-channel tile).
// Scalar loads coalesced along c; LDS [64][50] (stride-50 writes = 2-way
// bank alias, free); stores coalesced in 49-float runs along ij.
// ---------------------------------------------------------------------------
__global__ __launch_bounds__(256) void transpose_out(
    const float* __restrict__ outT, float* __restrict__ out)
{
    __shared__ float t[64][50];
    const int r   = blockIdx.x >> 2;
    const int c0  = (blockIdx.x & 3) * 64;
    const int tid = threadIdx.x;

    const float* src = outT + (size_t)r * 49 * N_C + c0;
    for (int k = tid; k < 49 * 64; k += 256) {
        const int ij = k >> 6;
        const int cl = k & 63;
        t[cl][ij] = src[(size_t)ij * N_C + cl];
    }
    __syncthreads();

    float* dst = out + ((size_t)r * N_C + c0) * 49;
    for (int k = tid; k < 64 * 49; k += 256) {
        const int cl = k / 49;
        const int ij = k - cl * 49;
        dst[(size_t)cl * 49 + ij] = t[cl][ij];
    }
}

extern "C" void kernel_launch(void* const* d_in, const int* in_sizes, int n_in,
                              void* d_out, int out_size, void* d_ws, size_t ws_size,
                              hipStream_t stream) {
    const float* feat = (const float*)d_in[0];
    const float* rois = (const float*)d_in[1];
    float* out   = (float*)d_out;
    float* featT = (float*)d_ws;                         // 2.96 MB
    float4* outT = (float4*)((float*)d_ws + OUTT_OFF);   // 12.85 MB (16B-aligned)

    transpose_nchw_nhwc<<<N_IMG * 23 * 4, 256, 0, stream>>>(feat, featT);
    roi_pool_wavepos<<<N_OUT_POS / 4, 256, 0, stream>>>(featT, rois, outT);
    transpose_out<<<NUM_ROIS * 4, 256, 0, stream>>>((const float*)outT, out);
}